// Round 1
// baseline (80.108 us; speedup 1.0000x reference)
//
#include <hip/hip_runtime.h>

#define Bn 8
#define Hn 128
#define Wn 128
#define Cn 64
#define NHEADS 4
#define Dn 16
#define NS 26           // 5*5 neighbors + self
#define TILE 16
#define HALO 20         // TILE + 2*2

__global__ __launch_bounds__(256, 2)
void local_attn_fused(const float* __restrict__ mainp,
                      const float* __restrict__ refp,
                      const float* __restrict__ Wm,
                      const float* __restrict__ Wr,
                      float* __restrict__ out)
{
    // k tile: 4 float4 planes [dq][row][col], col padded to 21 to break
    // bank aliasing (row stride 84 words == 20 mod 32 -> rows hit distinct
    // bank quads). 6720 floats = 26880 B; reused for output staging (6656 f).
    __shared__ __align__(16) float smem[4 * HALO * (HALO + 1) * 4];
    float4 (*sK)[HALO][HALO + 1] = (float4 (*)[HALO][HALO + 1])smem;

    const int tid = threadIdx.x;
    const int tx  = tid & (TILE - 1);
    const int ty  = tid >> 4;
    const int b   = blockIdx.z;
    const int y0  = blockIdx.y * TILE;
    const int x0  = blockIdx.x * TILE;
    const int y   = y0 + ty;
    const int x   = x0 + tx;

    const float4* mp4 = (const float4*)(mainp + (((size_t)b * Hn + y) * Wn + x) * Cn);

    float attn[NS];
#pragma unroll
    for (int i = 0; i < NS; ++i) attn[i] = 0.f;

    for (int h = 0; h < NHEADS; ++h) {
        const float* wmh = Wm + h * Cn * Dn;   // wave-uniform -> s_load
        const float* wrh = Wr + h * Cn * Dn;

        __syncthreads();   // protect sK from previous head's readers

        // ---- k projection for 20x20 halo tile (zero-padded SAME) ----
        for (int p = tid; p < HALO * HALO; p += 256) {
            const int hr = p / HALO;
            const int hc = p - hr * HALO;
            const int gy = y0 - 2 + hr;
            const int gx = x0 - 2 + hc;
            float kv[Dn];
#pragma unroll
            for (int d = 0; d < Dn; ++d) kv[d] = 0.f;
            if ((unsigned)gy < (unsigned)Hn && (unsigned)gx < (unsigned)Wn) {
                const float4* rp4 =
                    (const float4*)(refp + (((size_t)b * Hn + gy) * Wn + gx) * Cn);
#pragma unroll
                for (int c4 = 0; c4 < Cn / 4; ++c4) {
                    const float4 rv = rp4[c4];
                    const float rj[4] = {rv.x, rv.y, rv.z, rv.w};
#pragma unroll
                    for (int j = 0; j < 4; ++j) {
                        const float* wrow = wrh + (c4 * 4 + j) * Dn;
#pragma unroll
                        for (int d = 0; d < Dn; ++d)
                            kv[d] = fmaf(rj[j], wrow[d], kv[d]);
                    }
                }
            }
            sK[0][hr][hc] = make_float4(kv[0],  kv[1],  kv[2],  kv[3]);
            sK[1][hr][hc] = make_float4(kv[4],  kv[5],  kv[6],  kv[7]);
            sK[2][hr][hc] = make_float4(kv[8],  kv[9],  kv[10], kv[11]);
            sK[3][hr][hc] = make_float4(kv[12], kv[13], kv[14], kv[15]);
        }

        // ---- q projection for this thread's pixel ----
        float q[Dn];
#pragma unroll
        for (int d = 0; d < Dn; ++d) q[d] = 0.f;
#pragma unroll
        for (int c4 = 0; c4 < Cn / 4; ++c4) {
            const float4 mv = mp4[c4];
            const float mj[4] = {mv.x, mv.y, mv.z, mv.w};
#pragma unroll
            for (int j = 0; j < 4; ++j) {
                const float* wrow = wmh + (c4 * 4 + j) * Dn;
#pragma unroll
                for (int d = 0; d < Dn; ++d)
                    q[d] = fmaf(mj[j], wrow[d], q[d]);
            }
        }

        __syncthreads();

        // ---- 25 neighbor scores + self score ----
        float sc[NS];
#pragma unroll
        for (int di = 0; di < 5; ++di) {
#pragma unroll
            for (int dj = 0; dj < 5; ++dj) {
                const int r = ty + di;
                const int c = tx + dj;
                const float4 k0 = sK[0][r][c];
                const float4 k1 = sK[1][r][c];
                const float4 k2 = sK[2][r][c];
                const float4 k3 = sK[3][r][c];
                float s;
                s = q[0] * k0.x;
                s = fmaf(q[1],  k0.y, s);
                s = fmaf(q[2],  k0.z, s);
                s = fmaf(q[3],  k0.w, s);
                s = fmaf(q[4],  k1.x, s);
                s = fmaf(q[5],  k1.y, s);
                s = fmaf(q[6],  k1.z, s);
                s = fmaf(q[7],  k1.w, s);
                s = fmaf(q[8],  k2.x, s);
                s = fmaf(q[9],  k2.y, s);
                s = fmaf(q[10], k2.z, s);
                s = fmaf(q[11], k2.w, s);
                s = fmaf(q[12], k3.x, s);
                s = fmaf(q[13], k3.y, s);
                s = fmaf(q[14], k3.z, s);
                s = fmaf(q[15], k3.w, s);
                sc[di * 5 + dj] = s;
            }
        }
        {
            float s = q[0] * q[0];
#pragma unroll
            for (int d = 1; d < Dn; ++d) s = fmaf(q[d], q[d], s);
            sc[25] = s;
        }

        // ---- per-head softmax, accumulate head-mean ----
        float mx = sc[0];
#pragma unroll
        for (int i = 1; i < NS; ++i) mx = fmaxf(mx, sc[i]);
        float ssum = 0.f;
#pragma unroll
        for (int i = 0; i < NS; ++i) { sc[i] = __expf(sc[i] - mx); ssum += sc[i]; }
        const float inv = 1.0f / ssum;
#pragma unroll
        for (int i = 0; i < NS; ++i) attn[i] = fmaf(sc[i], inv, attn[i]);
    }

    // ---- coalesced output via LDS staging (reuse sK memory) ----
    __syncthreads();
    float* sO = smem;
#pragma unroll
    for (int i = 0; i < NS; ++i) sO[(ty * TILE + tx) * NS + i] = attn[i] * 0.25f;
    __syncthreads();
    const int rowlen = TILE * NS;            // 416 contiguous floats per row
    for (int idx = tid; idx < TILE * rowlen; idx += 256) {
        const int row = idx / rowlen;
        const int col = idx - row * rowlen;
        out[(((size_t)b * Hn + (y0 + row)) * Wn + x0) * NS + col] = sO[idx];
    }
}

extern "C" void kernel_launch(void* const* d_in, const int* in_sizes, int n_in,
                              void* d_out, int out_size, void* d_ws, size_t ws_size,
                              hipStream_t stream) {
    (void)in_sizes; (void)n_in; (void)d_ws; (void)ws_size; (void)out_size;
    const float* mainp = (const float*)d_in[0];
    const float* refp  = (const float*)d_in[1];
    const float* Wm    = (const float*)d_in[2];
    const float* Wr    = (const float*)d_in[3];
    float* out = (float*)d_out;
    dim3 grid(Wn / TILE, Hn / TILE, Bn);   // 8 x 8 x 8 = 512 blocks
    local_attn_fused<<<grid, 256, 0, stream>>>(mainp, refp, Wm, Wr, out);
}